// Round 3
// baseline (704.103 us; speedup 1.0000x reference)
//
#include <hip/hip_runtime.h>

#define N_NODES 16384
#define E_EDGES 524288
#define HID 128

typedef __attribute__((ext_vector_type(8))) short bf16x8;
typedef __attribute__((ext_vector_type(4))) float f32x4;

__device__ __forceinline__ unsigned short f2bf(float x) {
    unsigned u = __builtin_bit_cast(unsigned, x);
    u = u + 0x7fff + ((u >> 16) & 1);
    return (unsigned short)(u >> 16);
}
__device__ __forceinline__ float bf2f(unsigned short h) {
    return __builtin_bit_cast(float, (unsigned)h << 16);
}

// ---------------- CSR build ----------------

__global__ __launch_bounds__(256) void k_zero(int* __restrict__ cnt) {
    int i = blockIdx.x * 256 + threadIdx.x;
    if (i < N_NODES) cnt[i] = 0;
}

__global__ __launch_bounds__(256) void k_count(const int* __restrict__ ei, int* __restrict__ cnt) {
    int e = blockIdx.x * 256 + threadIdx.x;
    if (e < E_EDGES) {
        int d = ei[E_EDGES + e];
        atomicAdd(&cnt[d], 1);
    }
}

__global__ __launch_bounds__(1024) void k_scan(const int* __restrict__ cnt, int* __restrict__ rp,
                                               int* __restrict__ cur, float* __restrict__ dinv) {
    __shared__ int part[1024];
    int t = threadIdx.x;
    int base = t * 16;
    int loc[16];
    int s = 0;
#pragma unroll
    for (int i = 0; i < 16; ++i) { loc[i] = cnt[base + i]; s += loc[i]; }
    part[t] = s;
    __syncthreads();
    for (int off = 1; off < 1024; off <<= 1) {
        int add = (t >= off) ? part[t - off] : 0;
        __syncthreads();
        part[t] += add;
        __syncthreads();
    }
    int excl = (t == 0) ? 0 : part[t - 1];
#pragma unroll
    for (int i = 0; i < 16; ++i) {
        rp[base + i] = excl;
        cur[base + i] = excl;
        dinv[base + i] = rsqrtf((float)(loc[i] + 1));  // +1 self-loop
        excl += loc[i];
    }
    if (t == 1023) rp[N_NODES] = excl;
}

__global__ __launch_bounds__(256) void k_fill(const int* __restrict__ ei, int* __restrict__ cur,
                                              int* __restrict__ eidx) {
    int e = blockIdx.x * 256 + threadIdx.x;
    if (e < E_EDGES) {
        int s = ei[e];
        int d = ei[E_EDGES + e];
        int p = atomicAdd(&cur[d], 1);
        eidx[p] = s;
    }
}

// ---------------- layer GEMMs (fp32, small share of runtime) ----------------

__global__ __launch_bounds__(256) void k_gemm16(const float* __restrict__ X, const float* __restrict__ W,
                                                float* __restrict__ T) {
    __shared__ float sW[16 * 128];
    int t = threadIdx.x;
#pragma unroll
    for (int i = 0; i < 8; ++i) sW[i * 256 + t] = W[i * 256 + t];
    __syncthreads();
    int row = blockIdx.x * 2 + (t >> 7);
    int c = t & 127;
    const float* xr = X + row * 16;
    float acc = 0.f;
#pragma unroll
    for (int k = 0; k < 16; ++k) acc = fmaf(xr[k], sW[k * 128 + c], acc);
    T[row * HID + c] = acc;
}

__global__ __launch_bounds__(256) void k_gemm128(const float* __restrict__ A, const float* __restrict__ W,
                                                 float* __restrict__ T) {
    __shared__ float sA[64][132];
    __shared__ float sW[128][132];
    int t = threadIdx.x;
    int bm = blockIdx.x * 64;
#pragma unroll
    for (int it = 0; it < 8; ++it) {
        int f = it * 256 + t;
        int m = f >> 5, k4 = f & 31;
        *(float4*)(&sA[m][k4 * 4]) = *(const float4*)(A + (bm + m) * HID + k4 * 4);
    }
#pragma unroll
    for (int it = 0; it < 16; ++it) {
        int f = it * 256 + t;
        int k = f >> 5, n4 = f & 31;
        *(float4*)(&sW[k][n4 * 4]) = *(const float4*)(W + k * HID + n4 * 4);
    }
    __syncthreads();
    int tx = t & 15, ty = t >> 4;
    float acc[4][8] = {};
    for (int k4 = 0; k4 < 32; ++k4) {
        float4 a[4], b0[4], b1[4];
#pragma unroll
        for (int i = 0; i < 4; ++i) a[i] = *(const float4*)(&sA[ty * 4 + i][k4 * 4]);
#pragma unroll
        for (int kk = 0; kk < 4; ++kk) {
            b0[kk] = *(const float4*)(&sW[k4 * 4 + kk][tx * 4]);
            b1[kk] = *(const float4*)(&sW[k4 * 4 + kk][tx * 4 + 64]);
        }
#pragma unroll
        for (int kk = 0; kk < 4; ++kk) {
#pragma unroll
            for (int i = 0; i < 4; ++i) {
                float av = reinterpret_cast<const float*>(&a[i])[kk];
#pragma unroll
                for (int j = 0; j < 4; ++j) {
                    acc[i][j]     = fmaf(av, reinterpret_cast<const float*>(&b0[kk])[j], acc[i][j]);
                    acc[i][4 + j] = fmaf(av, reinterpret_cast<const float*>(&b1[kk])[j], acc[i][4 + j]);
                }
            }
        }
    }
#pragma unroll
    for (int i = 0; i < 4; ++i) {
        int row = bm + ty * 4 + i;
        float4 o0, o1;
        o0.x = acc[i][0]; o0.y = acc[i][1]; o0.z = acc[i][2]; o0.w = acc[i][3];
        o1.x = acc[i][4]; o1.y = acc[i][5]; o1.z = acc[i][6]; o1.w = acc[i][7];
        *(float4*)(T + row * HID + tx * 4) = o0;
        *(float4*)(T + row * HID + tx * 4 + 64) = o1;
    }
}

// ---------------- aggregation ----------------
__global__ __launch_bounds__(128) void k_agg(const float* __restrict__ T, const int* __restrict__ rp,
                                             const int* __restrict__ eidx, const float* __restrict__ dinv,
                                             const float* __restrict__ b, float* __restrict__ H) {
    __shared__ int se[128];
    __shared__ float sw[128];
    int i = blockIdx.x;
    int c = threadIdx.x;
    float di = dinv[i];
    float acc = di * T[i * HID + c];
    int beg = rp[i], end = rp[i + 1];
    for (int base = beg; base < end; base += 128) {
        int e = base + c;
        if (e < end) {
            int s = eidx[e];
            se[c] = s;
            sw[c] = dinv[s];
        }
        __syncthreads();
        int n = min(128, end - base);
        for (int j = 0; j < n; ++j) {
            acc += sw[j] * T[se[j] * HID + c];
        }
        __syncthreads();
    }
    float v = fmaf(di, acc, b[c]);
    H[i * HID + c] = fmaxf(v, 0.0f);
}

// ---------------- bf16 split prep ----------------

__global__ __launch_bounds__(256) void k_split_a(const float* __restrict__ A,
                                                 unsigned short* __restrict__ hi,
                                                 unsigned short* __restrict__ lo) {
    int i = (blockIdx.x * 256 + threadIdx.x) * 8;
    float4 v0 = *(const float4*)(A + i);
    float4 v1 = *(const float4*)(A + i + 4);
    float v[8] = {v0.x, v0.y, v0.z, v0.w, v1.x, v1.y, v1.z, v1.w};
    alignas(16) unsigned short hb[8], lb[8];
#pragma unroll
    for (int j = 0; j < 8; ++j) {
        unsigned short h = f2bf(v[j]);
        hb[j] = h;
        lb[j] = f2bf(v[j] - bf2f(h));
    }
    *(uint4*)(hi + i) = *(uint4*)hb;
    *(uint4*)(lo + i) = *(uint4*)lb;
}

// W[128, N] fp32 -> transposed hi/lo bf16 [N,128] (K contiguous)
__global__ __launch_bounds__(256) void k_split_b(const float* __restrict__ W,
                                                 unsigned short* __restrict__ bhi,
                                                 unsigned short* __restrict__ blo) {
    __shared__ float sm[32][132];
    int t = threadIdx.x;
    int nb = blockIdx.x;   // 0..127
    int kb = blockIdx.y;   // 0..3
#pragma unroll
    for (int i = 0; i < 4; ++i) {
        int idx = i * 256 + t;
        int k = idx >> 5, n4 = idx & 31;
        *(float4*)(&sm[k][n4 * 4]) =
            *(const float4*)(W + (size_t)(kb * 32 + k) * N_NODES + nb * 128 + n4 * 4);
    }
    __syncthreads();
    int n = t >> 1, half = t & 1;
    alignas(16) unsigned short hb[16], lb[16];
#pragma unroll
    for (int j = 0; j < 16; ++j) {
        float x = sm[half * 16 + j][n];
        unsigned short h = f2bf(x);
        hb[j] = h;
        lb[j] = f2bf(x - bf2f(h));
    }
    size_t o = (size_t)(nb * 128 + n) * 128 + kb * 32 + half * 16;
    *(uint4*)(bhi + o) = *(uint4*)hb;
    *(uint4*)(bhi + o + 8) = *(uint4*)(hb + 8);
    *(uint4*)(blo + o) = *(uint4*)lb;
    *(uint4*)(blo + o + 8) = *(uint4*)(lb + 8);
}

// ---------------- final FC via MFMA, split-bf16, LDS-free ----------------
// C[16384,16384] = A[16384,128] @ Wfc[128,16384] + bias
// Operands are small (16.8 MB total) and L2/L3-resident with 128x reuse:
// load MFMA fragments directly global->VGPR. No LDS, no barriers.
// Each wave owns a 64x64 output tile; 2x2 waves per block -> 128x128/block.
__global__ __launch_bounds__(256) void k_fc_mfma(const unsigned short* __restrict__ Ahi,
                                                 const unsigned short* __restrict__ Alo,
                                                 const unsigned short* __restrict__ Bhi,
                                                 const unsigned short* __restrict__ Blo,
                                                 const float* __restrict__ bias,
                                                 float* __restrict__ C) {
    int t = threadIdx.x;
    int wid = t >> 6, lane = t & 63;
    int wm = wid >> 1, wn = wid & 1;
    int row16 = lane & 15, kq = lane >> 4;
    int m0 = blockIdx.y * 128 + wm * 64;
    int n0 = blockIdx.x * 128 + wn * 64;

    // fragment base pointers: row (m0/n0 + row16), k-offset kq*8
    const unsigned short* pah = Ahi + (size_t)(m0 + row16) * HID + kq * 8;
    const unsigned short* pal = Alo + (size_t)(m0 + row16) * HID + kq * 8;
    const unsigned short* pbh = Bhi + (size_t)(n0 + row16) * HID + kq * 8;
    const unsigned short* pbl = Blo + (size_t)(n0 + row16) * HID + kq * 8;

    f32x4 acc[4][4] = {};
#pragma unroll
    for (int ks = 0; ks < 4; ++ks) {
        bf16x8 ah[4], al[4];
#pragma unroll
        for (int m = 0; m < 4; ++m) {
            ah[m] = *(const bf16x8*)(pah + m * 16 * HID + ks * 32);
            al[m] = *(const bf16x8*)(pal + m * 16 * HID + ks * 32);
        }
#pragma unroll
        for (int n = 0; n < 4; ++n) {
            bf16x8 bh = *(const bf16x8*)(pbh + n * 16 * HID + ks * 32);
            bf16x8 bl = *(const bf16x8*)(pbl + n * 16 * HID + ks * 32);
            // independent-acc groups first, dependent chains spread apart
#pragma unroll
            for (int m = 0; m < 4; ++m)
                acc[m][n] = __builtin_amdgcn_mfma_f32_16x16x32_bf16(ah[m], bh, acc[m][n], 0, 0, 0);
#pragma unroll
            for (int m = 0; m < 4; ++m)
                acc[m][n] = __builtin_amdgcn_mfma_f32_16x16x32_bf16(ah[m], bl, acc[m][n], 0, 0, 0);
#pragma unroll
            for (int m = 0; m < 4; ++m)
                acc[m][n] = __builtin_amdgcn_mfma_f32_16x16x32_bf16(al[m], bh, acc[m][n], 0, 0, 0);
        }
    }

    // epilogue: C/D layout col=lane&15, row=(lane>>4)*4+reg  [m89-verified]
    // nontemporal: keep the 1 GB output stream from evicting A/B in L2
#pragma unroll
    for (int n = 0; n < 4; ++n) {
        int col = n0 + n * 16 + row16;
        float bv = bias[col];
#pragma unroll
        for (int m = 0; m < 4; ++m) {
            int r0 = m0 + m * 16 + kq * 4;
#pragma unroll
            for (int r = 0; r < 4; ++r)
                __builtin_nontemporal_store(acc[m][n][r] + bv,
                                            C + (size_t)(r0 + r) * N_NODES + col);
        }
    }
}

// ---------------- launch ----------------

extern "C" void kernel_launch(void* const* d_in, const int* in_sizes, int n_in,
                              void* d_out, int out_size, void* d_ws, size_t ws_size,
                              hipStream_t stream) {
    const float* x   = (const float*)d_in[0];
    const int*   ei  = (const int*)d_in[1];
    const float* W1  = (const float*)d_in[2];
    const float* b1  = (const float*)d_in[3];
    const float* W2  = (const float*)d_in[4];
    const float* b2  = (const float*)d_in[5];
    const float* W3  = (const float*)d_in[6];
    const float* b3  = (const float*)d_in[7];
    const float* Wfc = (const float*)d_in[8];
    const float* bfc = (const float*)d_in[9];
    float* out = (float*)d_out;

    char* ws = (char*)d_ws;
    int* cnt  = (int*)ws;                   // 16384
    int* rp   = cnt + N_NODES;              // 16385 (+pad)
    int* cur  = rp + N_NODES + 64;          // 16384
    int* eidx = cur + N_NODES;              // E
    float* dinv = (float*)(eidx + E_EDGES); // 16384
    float* t  = dinv + N_NODES;             // N*128 fp32
    float* h  = t + N_NODES * HID;          // N*128 fp32
    unsigned short* ahi = (unsigned short*)t;            // N*128 bf16 (t dead after last agg)
    unsigned short* alo = ahi + N_NODES * HID;
    unsigned short* bhi = (unsigned short*)(h + N_NODES * HID);
    unsigned short* blo = bhi + N_NODES * HID;

    k_zero<<<N_NODES / 256, 256, 0, stream>>>(cnt);
    k_count<<<E_EDGES / 256, 256, 0, stream>>>(ei, cnt);
    k_scan<<<1, 1024, 0, stream>>>(cnt, rp, cur, dinv);
    k_fill<<<E_EDGES / 256, 256, 0, stream>>>(ei, cur, eidx);

    // layers
    k_gemm16<<<N_NODES / 2, 256, 0, stream>>>(x, W1, t);
    k_agg<<<N_NODES, 128, 0, stream>>>(t, rp, eidx, dinv, b1, h);
    k_gemm128<<<N_NODES / 64, 256, 0, stream>>>(h, W2, t);
    k_agg<<<N_NODES, 128, 0, stream>>>(t, rp, eidx, dinv, b2, h);
    k_gemm128<<<N_NODES / 64, 256, 0, stream>>>(h, W3, t);
    k_agg<<<N_NODES, 128, 0, stream>>>(t, rp, eidx, dinv, b3, h);

    // FC prep: split h and Wfc^T into bf16 hi/lo
    k_split_b<<<dim3(N_NODES / 128, HID / 32), 256, 0, stream>>>(Wfc, bhi, blo);
    k_split_a<<<(N_NODES * HID) / (256 * 8), 256, 0, stream>>>(h, ahi, alo);

    // final FC
    k_fc_mfma<<<dim3(N_NODES / 128, N_NODES / 128), 256, 0, stream>>>(ahi, alo, bhi, blo, bfc, out);
}